// Round 8
// baseline (251.072 us; speedup 1.0000x reference)
//
#include <hip/hip_runtime.h>
#include <cstdint>
#include <cmath>

#define B_ 128
#define P_ 8732
#define HALF_ 4366
#define M_ 16
#define NT 1024
#define NW (NT / 64)   // 16 waves == M_ objects
#define NP9 9          // ceil(P_/NT)

__device__ __forceinline__ float softplusf(float x) {
    // logaddexp(0, x) = max(x,0) + log1p(exp(-|x|))
    return fmaxf(x, 0.0f) + log1pf(expf(-fabsf(x)));
}

__device__ __forceinline__ float wred_sum_f(float v) {
#pragma unroll
    for (int o = 32; o > 0; o >>= 1) v += __shfl_down(v, o, 64);
    return v;
}
__device__ __forceinline__ int wred_sum_i(int v) {
#pragma unroll
    for (int o = 32; o > 0; o >>= 1) v += __shfl_down(v, o, 64);
    return v;
}

// Grid = 256 blocks: block bk handles row r = bk>>1, half h = bk&1 for the
// matching stage (A/B). The SECOND block of each pair to finish (atomic
// ticket) continues into C/D/E for the whole row. No spinning -> no
// co-residency assumption needed.
__global__ __launch_bounds__(NT) void mbox_kernel(
    const float* __restrict__ plocs,   // (B,P,4)
    const float* __restrict__ pscores, // (B,P,3)
    const float* __restrict__ boxes,   // (B,M,4) xyxy
    const int*   __restrict__ labels,  // (B,M)
    const float* __restrict__ priors,  // (P,4) cxcy
    float* __restrict__ out,           // [total, conf, loc, npos x 128]
    unsigned int* __restrict__ g_cnt,  // ws: final-reduction counter
    float* __restrict__ g_conf,        // ws
    float* __restrict__ g_loc,         // ws
    int*   __restrict__ g_np,          // ws
    unsigned int* __restrict__ row_cnt,// ws: per-row ticket [128]
    int2*  __restrict__ cand,          // ws: per (block,m) best-prior cand [256*16]
    unsigned char* __restrict__ objov) // ws: per (row,prior) bit7=pos, 0-3=obj [128*P_]
{
    __shared__ float s_boxes[M_ * 4];
    __shared__ float s_area[M_];
    __shared__ int   s_labels[M_];
    __shared__ int   s_prior_obj[M_];
    __shared__ float s_pf[2 * NW];        // partial sums (conf, loc)
    __shared__ int   s_pi[NW];            // partial counts
    __shared__ int   s_cnt2[2][NW];       // bisection partials, parity-buffered
    __shared__ float s_scal[2];
    __shared__ int   s_npos;
    __shared__ unsigned int s_old;

    const int bk = blockIdx.x;
    const int r  = bk >> 1;
    const int h  = bk & 1;
    const int tid = threadIdx.x;
    const int lane = tid & 63;
    const int wid = tid >> 6;

    if (tid < M_ * 4) s_boxes[tid] = boxes[r * M_ * 4 + tid];
    if (tid >= 64 && tid < 64 + M_) s_labels[tid - 64] = labels[r * M_ + (tid - 64)];
    __syncthreads();
    if (tid < M_) {
        float x0 = s_boxes[tid*4+0], y0 = s_boxes[tid*4+1];
        float x1 = s_boxes[tid*4+2], y1 = s_boxes[tid*4+3];
        s_area[tid] = (x1 - x0) * (y1 - y0);
    }
    __syncthreads();

    const int p0 = h * HALF_;

    // ---- Phase A (half row): per-prior best object -> packed byte to ws
    for (int p = p0 + tid; p < p0 + HALF_; p += NT) {
        float4 pr = ((const float4*)priors)[p];
        float px0 = pr.x - pr.z * 0.5f;
        float py0 = pr.y - pr.w * 0.5f;
        float px1 = pr.x + pr.z * 0.5f;
        float py1 = pr.y + pr.w * 0.5f;
        float parea = pr.z * pr.w;
        float bestv = -1.0f; int besti = 0;
#pragma unroll
        for (int m = 0; m < M_; ++m) {
            float ltx = fmaxf(s_boxes[m*4+0], px0);
            float lty = fmaxf(s_boxes[m*4+1], py0);
            float rbx = fminf(s_boxes[m*4+2], px1);
            float rby = fminf(s_boxes[m*4+3], py1);
            float wx = fmaxf(rbx - ltx, 0.0f);
            float wy = fmaxf(rby - lty, 0.0f);
            float inter = wx * wy;
            float ov = inter * __builtin_amdgcn_rcpf(s_area[m] + parea - inter);
            if (ov > bestv) { bestv = ov; besti = m; }       // first-max over m
        }
        objov[(size_t)r * P_ + p] =
            (unsigned char)(besti | (bestv >= 0.5f ? 0x80 : 0));
    }

    // ---- Phase B (half row): one WAVE per object, wave-argmax -> candidate
    {
        const int m = wid;               // NW == M_
        float bx0 = s_boxes[m*4+0], by0 = s_boxes[m*4+1];
        float bx1 = s_boxes[m*4+2], by1 = s_boxes[m*4+3];
        float marea = s_area[m];
        float bv = -1.0f; int bi = 0x7FFFFFFF;
        for (int p = p0 + lane; p < p0 + HALF_; p += 64) {
            float4 pr = ((const float4*)priors)[p];
            float px0 = pr.x - pr.z * 0.5f;
            float py0 = pr.y - pr.w * 0.5f;
            float px1 = pr.x + pr.z * 0.5f;
            float py1 = pr.y + pr.w * 0.5f;
            float ltx = fmaxf(bx0, px0);
            float lty = fmaxf(by0, py0);
            float rbx = fminf(bx1, px1);
            float rby = fminf(by1, py1);
            float wx = fmaxf(rbx - ltx, 0.0f);
            float wy = fmaxf(rby - lty, 0.0f);
            float inter = wx * wy;
            float ov = inter * __builtin_amdgcn_rcpf(marea + pr.z * pr.w - inter);
            if (ov > bv) { bv = ov; bi = p; }   // first-max (p ascending per lane)
        }
#pragma unroll
        for (int o = 32; o > 0; o >>= 1) {
            float v2 = __shfl_down(bv, o, 64);
            int   i2 = __shfl_down(bi, o, 64);
            if (v2 > bv || (v2 == bv && i2 < bi)) { bv = v2; bi = i2; }
        }
        if (lane == 0) cand[bk * M_ + m] = make_int2(__float_as_int(bv), bi);
    }

    // ---- ticket gate: second finisher of the pair continues
    __syncthreads();                      // all waves' global stores drained
    __threadfence();                      // release (agent scope, cross-XCD)
    if (tid == 0) s_old = atomicAdd(&row_cnt[r], 1u);
    __syncthreads();
    if (s_old == 0) return;               // first finisher exits
    __threadfence();                      // acquire

    // ---- combine the two halves' per-object candidates (first-max overall)
    if (tid < M_) {
        int2 c0 = cand[(r * 2) * M_ + tid];
        int2 c1 = cand[(r * 2 + 1) * M_ + tid];
        float v0 = __int_as_float(c0.x), v1 = __int_as_float(c1.x);
        s_prior_obj[tid] = (v1 > v0) ? c1.y : c0.y;   // half0 wins ties (lower p)
    }
    __syncthreads();

    // ---- Phase C: fixup scatter (serial, last m wins on duplicate priors)
    if (tid == 0) {
        for (int m = 0; m < M_; ++m)
            objov[(size_t)r * P_ + s_prior_obj[m]] = (unsigned char)(0x80 | m);
    }
    __syncthreads();   // drains tid0's stores; same-CU read-after-write below

    // ---- Phase D: labels, BCE, L1 on positives; bce_neg kept in REGISTERS
    float fv[NP9];   // conf_neg values (0 at positives / invalid)
    int   n_pos = 0;
    float conf_pos = 0.0f;
    float loc_sum = 0.0f;
#pragma unroll
    for (int i = 0; i < NP9; ++i) {
        fv[i] = 0.0f;
        int p = tid + i * NT;
        if (p < P_) {
            unsigned char byte = objov[(size_t)r * P_ + p];
            int obj = byte & 15;
            bool pos = (byte & 0x80) != 0;
            int lab = pos ? s_labels[obj] : 0;
            const float* sc = pscores + ((size_t)r * P_ + p) * 3;
            float x0 = sc[0], x1 = sc[1], x2 = sc[2];
            float t0 = (lab == 0) ? 1.0f : 0.0f;
            float t1 = (lab == 1 || lab == 3) ? 1.0f : 0.0f;
            float t2 = (lab == 2 || lab == 3) ? 1.0f : 0.0f;
            float bce = (softplusf(x0) - x0*t0) + (softplusf(x1) - x1*t1) + (softplusf(x2) - x2*t2);
            if (pos) {
                n_pos++;
                conf_pos += bce;
                float4 pr = ((const float4*)priors)[p];
                float bx0 = s_boxes[obj*4+0], by0 = s_boxes[obj*4+1];
                float bx1 = s_boxes[obj*4+2], by1 = s_boxes[obj*4+3];
                float cx = (bx0 + bx1) * 0.5f, cy = (by0 + by1) * 0.5f;
                float w = bx1 - bx0, hh = by1 - by0;
                float g0 = (cx - pr.x) / (pr.z * 0.1f);
                float g1 = (cy - pr.y) / (pr.w * 0.1f);
                float g2 = logf(w / pr.z) * 5.0f;
                float g3 = logf(hh / pr.w) * 5.0f;
                float4 pl = ((const float4*)plocs)[(size_t)r * P_ + p];
                loc_sum += fabsf(pl.x - g0) + fabsf(pl.y - g1) + fabsf(pl.z - g2) + fabsf(pl.w - g3);
            } else {
                fv[i] = bce;
            }
        }
    }

    // ---- reduce n_pos, conf_pos, loc_sum (wave shuffle + cross-wave)
    {
        float cp = wred_sum_f(conf_pos);
        float ls = wred_sum_f(loc_sum);
        int   np = wred_sum_i(n_pos);
        if (lane == 0) { s_pf[wid] = cp; s_pf[NW + wid] = ls; s_pi[wid] = np; }
    }
    __syncthreads();
    if (tid == 0) {
        float cp = 0.0f, ls = 0.0f; int np = 0;
#pragma unroll
        for (int w = 0; w < NW; ++w) { cp += s_pf[w]; ls += s_pf[NW + w]; np += s_pi[w]; }
        s_scal[0] = cp; s_scal[1] = ls; s_npos = np;
    }
    __syncthreads();
    const int npos_row = s_npos;

    // ---- Phase E: exact top-k via bit-pattern bisection; state replicated per
    //      thread (deterministic), parity-buffered partials -> 1 barrier/iter.
    int k = 3 * npos_row;
    if (k > P_) k = P_;
    float hard_sum = 0.0f;
    if (k > 0) {
        long long lo = -1, hi = 0x7F800000LL;   // invariant: cnt(lo)>=k, cnt(hi)<k
        for (int it = 0; it < 31; ++it) {
            unsigned int mid = (unsigned int)((lo + hi) >> 1);
            int c = 0;
#pragma unroll
            for (int i = 0; i < NP9; ++i) c += (__float_as_uint(fv[i]) > mid) ? 1 : 0;
            c = wred_sum_i(c);
            if (lane == 0) s_cnt2[it & 1][wid] = c;
            __syncthreads();
            int cnt = 0;
#pragma unroll
            for (int w = 0; w < NW; ++w) cnt += s_cnt2[it & 1][w];
            if (cnt < k) hi = (lo + hi) >> 1; else lo = (lo + hi) >> 1;
        }
        unsigned int tbits = (unsigned int)hi;   // k-th largest bit pattern, exact
        float tval = __uint_as_float(tbits);
        float lsum = 0.0f; int lcnt = 0;
#pragma unroll
        for (int i = 0; i < NP9; ++i) {
            if (__float_as_uint(fv[i]) > tbits) { lsum += fv[i]; lcnt++; }
        }
        lsum = wred_sum_f(lsum);
        lcnt = wred_sum_i(lcnt);
        if (lane == 0) { s_pf[wid] = lsum; s_pi[wid] = lcnt; }
        __syncthreads();
        if (tid == 0) {
            float sv = 0.0f; int sc2 = 0;
#pragma unroll
            for (int w = 0; w < NW; ++w) { sv += s_pf[w]; sc2 += s_pi[w]; }
            hard_sum = sv + (float)(k - sc2) * tval;
        }
    }

    // ---- finalize: per-row output + last-row global reduction
    if (tid == 0) {
        float conf_row = s_scal[0] + hard_sum;
        float loc_row  = s_scal[1];
        out[3 + r] = (float)npos_row;
        atomicAdd(g_conf, conf_row);
        atomicAdd(g_loc,  loc_row);
        atomicAdd(g_np,   npos_row);
        __threadfence();
        unsigned int done = atomicAdd(g_cnt, 1u);
        if (done == B_ - 1) {
            float ct = atomicAdd(g_conf, 0.0f);  // read at coherent point
            float lt = atomicAdd(g_loc,  0.0f);
            int   np = atomicAdd(g_np,   0);
            float npt = (float)np;
            float conf_loss = ct / (1e-10f + npt);
            float loc_loss = (np > 0) ? lt / (4.0f * fmaxf(npt, 1.0f)) : 0.0f;
            out[0] = conf_loss + loc_loss;   // ALPHA = 1
            out[1] = conf_loss;
            out[2] = loc_loss;
        }
    }
}

extern "C" void kernel_launch(void* const* d_in, const int* in_sizes, int n_in,
                              void* d_out, int out_size, void* d_ws, size_t ws_size,
                              hipStream_t stream) {
    const float* plocs   = (const float*)d_in[0];  // (B,P,4)
    const float* pscores = (const float*)d_in[1];  // (B,P,3)
    const float* boxes   = (const float*)d_in[2];  // (B,M,4)
    const int*   labels  = (const int*)  d_in[3];  // (B,M)
    const float* priors  = (const float*)d_in[4];  // (P,4)
    float* out = (float*)d_out;

    // ws layout:
    //   [0,16)        g_cnt, g_conf, g_loc, g_np
    //   [16,528)      row_cnt[128]
    //   [1024,33792)  cand[256*16] int2
    //   [33792, +128*P_) objov bytes  (~1.12 MB; total ws use ~1.16 MB)
    char* ws = (char*)d_ws;
    unsigned int* g_cnt   = (unsigned int*)ws;
    float*        g_conf  = (float*)(ws + 4);
    float*        g_loc   = (float*)(ws + 8);
    int*          g_np    = (int*)(ws + 12);
    unsigned int* row_cnt = (unsigned int*)(ws + 16);
    int2*         cand    = (int2*)(ws + 1024);
    unsigned char* objov  = (unsigned char*)(ws + 1024 + 2 * B_ * M_ * sizeof(int2));

    hipMemsetAsync(d_ws, 0, 1024, stream);   // zero counters + tickets
    mbox_kernel<<<2 * B_, NT, 0, stream>>>(plocs, pscores, boxes, labels, priors,
                                           out, g_cnt, g_conf, g_loc, g_np,
                                           row_cnt, cand, objov);
}

// Round 9
// 164.207 us; speedup vs baseline: 1.5290x; 1.5290x over previous
//
#include <hip/hip_runtime.h>
#include <cstdint>
#include <cmath>

#define B_ 128
#define P_ 8732
#define QU_ 2183        // P_ / 4 exactly
#define M_ 16
#define NT 1024
#define NW (NT / 64)    // 16 waves == M_ objects
#define NP9 9           // ceil(P_/NT)

__device__ __forceinline__ float softplusf(float x) {
    // logaddexp(0, x) = max(x,0) + log1p(exp(-|x|))
    return fmaxf(x, 0.0f) + log1pf(expf(-fabsf(x)));
}

__device__ __forceinline__ float wred_sum_f(float v) {
#pragma unroll
    for (int o = 32; o > 0; o >>= 1) v += __shfl_down(v, o, 64);
    return v;
}
__device__ __forceinline__ int wred_sum_i(int v) {
#pragma unroll
    for (int o = 32; o > 0; o >>= 1) v += __shfl_down(v, o, 64);
    return v;
}

// ---------------- K1: matching. grid = 512 blocks = (row, quarter). ----------
// Phase A: per-prior best object -> packed byte (bit7 = ov>=0.5, bits0-3 = m).
// Phase B: per-object best prior within the quarter -> cand[(row*4+q)*16 + m].
// No fences: the kernel boundary makes everything visible to K2.
__global__ __launch_bounds__(NT) void mbox_match_kernel(
    const float* __restrict__ boxes,   // (B,M,4) xyxy
    const float* __restrict__ priors,  // (P,4) cxcy
    unsigned char* __restrict__ objov, // ws: [B_*P_]
    int2* __restrict__ cand)           // ws: [512*M_]
{
    __shared__ float s_boxes[M_ * 4];
    __shared__ float s_area[M_];

    const int bk = blockIdx.x;
    const int r  = bk >> 2;
    const int q  = bk & 3;
    const int tid = threadIdx.x;
    const int lane = tid & 63;
    const int wid = tid >> 6;

    if (tid < M_ * 4) s_boxes[tid] = boxes[r * M_ * 4 + tid];
    __syncthreads();
    if (tid < M_) {
        float x0 = s_boxes[tid*4+0], y0 = s_boxes[tid*4+1];
        float x1 = s_boxes[tid*4+2], y1 = s_boxes[tid*4+3];
        s_area[tid] = (x1 - x0) * (y1 - y0);
    }
    __syncthreads();

    const int p0 = q * QU_;

    // ---- Phase A (quarter): per-prior best object
    for (int p = p0 + tid; p < p0 + QU_; p += NT) {
        float4 pr = ((const float4*)priors)[p];
        float px0 = pr.x - pr.z * 0.5f;
        float py0 = pr.y - pr.w * 0.5f;
        float px1 = pr.x + pr.z * 0.5f;
        float py1 = pr.y + pr.w * 0.5f;
        float parea = pr.z * pr.w;
        float bestv = -1.0f; int besti = 0;
#pragma unroll
        for (int m = 0; m < M_; ++m) {
            float ltx = fmaxf(s_boxes[m*4+0], px0);
            float lty = fmaxf(s_boxes[m*4+1], py0);
            float rbx = fminf(s_boxes[m*4+2], px1);
            float rby = fminf(s_boxes[m*4+3], py1);
            float wx = fmaxf(rbx - ltx, 0.0f);
            float wy = fmaxf(rby - lty, 0.0f);
            float inter = wx * wy;
            float ov = inter * __builtin_amdgcn_rcpf(s_area[m] + parea - inter);
            if (ov > bestv) { bestv = ov; besti = m; }       // first-max over m
        }
        objov[(size_t)r * P_ + p] =
            (unsigned char)(besti | (bestv >= 0.5f ? 0x80 : 0));
    }

    // ---- Phase B (quarter): one WAVE per object, wave-argmax
    {
        const int m = wid;               // NW == M_
        float bx0 = s_boxes[m*4+0], by0 = s_boxes[m*4+1];
        float bx1 = s_boxes[m*4+2], by1 = s_boxes[m*4+3];
        float marea = s_area[m];
        float bv = -1.0f; int bi = 0x7FFFFFFF;
        for (int p = p0 + lane; p < p0 + QU_; p += 64) {
            float4 pr = ((const float4*)priors)[p];
            float px0 = pr.x - pr.z * 0.5f;
            float py0 = pr.y - pr.w * 0.5f;
            float px1 = pr.x + pr.z * 0.5f;
            float py1 = pr.y + pr.w * 0.5f;
            float ltx = fmaxf(bx0, px0);
            float lty = fmaxf(by0, py0);
            float rbx = fminf(bx1, px1);
            float rby = fminf(by1, py1);
            float wx = fmaxf(rbx - ltx, 0.0f);
            float wy = fmaxf(rby - lty, 0.0f);
            float inter = wx * wy;
            float ov = inter * __builtin_amdgcn_rcpf(marea + pr.z * pr.w - inter);
            if (ov > bv) { bv = ov; bi = p; }   // first-max (p ascending per lane)
        }
#pragma unroll
        for (int o = 32; o > 0; o >>= 1) {
            float v2 = __shfl_down(bv, o, 64);
            int   i2 = __shfl_down(bi, o, 64);
            if (v2 > bv || (v2 == bv && i2 < bi)) { bv = v2; bi = i2; }
        }
        if (lane == 0) cand[bk * M_ + m] = make_int2(__float_as_int(bv), bi);
    }
}

// ---------------- K2: loss. grid = 128 blocks = row. -------------------------
__global__ __launch_bounds__(NT) void mbox_loss_kernel(
    const float* __restrict__ plocs,   // (B,P,4)
    const float* __restrict__ pscores, // (B,P,3)
    const float* __restrict__ boxes,   // (B,M,4)
    const int*   __restrict__ labels,  // (B,M)
    const float* __restrict__ priors,  // (P,4)
    unsigned char* __restrict__ objov, // ws (from K1)
    const int2* __restrict__ cand,     // ws (from K1)
    float* __restrict__ out,           // [total, conf, loc, npos x 128]
    unsigned int* __restrict__ g_cnt,
    float* __restrict__ g_conf,
    float* __restrict__ g_loc,
    int*   __restrict__ g_np)
{
    __shared__ float s_boxes[M_ * 4];
    __shared__ int   s_labels[M_];
    __shared__ int   s_prior_obj[M_];
    __shared__ float s_pf[2 * NW];
    __shared__ int   s_pi[NW];
    __shared__ int   s_cnt2[2][NW];
    __shared__ float s_scal[2];
    __shared__ int   s_npos;

    const int r = blockIdx.x;
    const int tid = threadIdx.x;
    const int lane = tid & 63;
    const int wid = tid >> 6;

    if (tid < M_ * 4) s_boxes[tid] = boxes[r * M_ * 4 + tid];
    if (tid >= 64 && tid < 64 + M_) s_labels[tid - 64] = labels[r * M_ + (tid - 64)];
    // ---- combine the 4 quarter-candidates per object (order-preserving ->
    //      exact first-max over p)
    if (tid >= 128 && tid < 128 + M_) {
        int m = tid - 128;
        int2 c = cand[(r * 4) * M_ + m];
        float v = __int_as_float(c.x); int idx = c.y;
#pragma unroll
        for (int qq = 1; qq < 4; ++qq) {
            int2 c2 = cand[(r * 4 + qq) * M_ + m];
            float v2 = __int_as_float(c2.x);
            if (v2 > v) { v = v2; idx = c2.y; }   // strict >: earliest quarter wins ties
        }
        s_prior_obj[m] = idx;
    }
    __syncthreads();

    // ---- fixup scatter (serial, last m wins on duplicate priors)
    if (tid == 0) {
        for (int m = 0; m < M_; ++m)
            objov[(size_t)r * P_ + s_prior_obj[m]] = (unsigned char)(0x80 | m);
    }
    __syncthreads();   // workgroup-scope release/acquire: same-block global RAW ok

    // ---- Phase D: labels, BCE, L1 on positives; bce_neg in registers
    float fv[NP9];
    int   n_pos = 0;
    float conf_pos = 0.0f;
    float loc_sum = 0.0f;
#pragma unroll
    for (int i = 0; i < NP9; ++i) {
        fv[i] = 0.0f;
        int p = tid + i * NT;
        if (p < P_) {
            unsigned char byte = objov[(size_t)r * P_ + p];
            int obj = byte & 15;
            bool pos = (byte & 0x80) != 0;
            int lab = pos ? s_labels[obj] : 0;
            const float* sc = pscores + ((size_t)r * P_ + p) * 3;
            float x0 = sc[0], x1 = sc[1], x2 = sc[2];
            float t0 = (lab == 0) ? 1.0f : 0.0f;
            float t1 = (lab == 1 || lab == 3) ? 1.0f : 0.0f;
            float t2 = (lab == 2 || lab == 3) ? 1.0f : 0.0f;
            float bce = (softplusf(x0) - x0*t0) + (softplusf(x1) - x1*t1) + (softplusf(x2) - x2*t2);
            if (pos) {
                n_pos++;
                conf_pos += bce;
                float4 pr = ((const float4*)priors)[p];
                float bx0 = s_boxes[obj*4+0], by0 = s_boxes[obj*4+1];
                float bx1 = s_boxes[obj*4+2], by1 = s_boxes[obj*4+3];
                float cx = (bx0 + bx1) * 0.5f, cy = (by0 + by1) * 0.5f;
                float w = bx1 - bx0, hh = by1 - by0;
                float g0 = (cx - pr.x) / (pr.z * 0.1f);
                float g1 = (cy - pr.y) / (pr.w * 0.1f);
                float g2 = logf(w / pr.z) * 5.0f;
                float g3 = logf(hh / pr.w) * 5.0f;
                float4 pl = ((const float4*)plocs)[(size_t)r * P_ + p];
                loc_sum += fabsf(pl.x - g0) + fabsf(pl.y - g1) + fabsf(pl.z - g2) + fabsf(pl.w - g3);
            } else {
                fv[i] = bce;
            }
        }
    }

    // ---- reduce n_pos, conf_pos, loc_sum
    {
        float cp = wred_sum_f(conf_pos);
        float ls = wred_sum_f(loc_sum);
        int   np = wred_sum_i(n_pos);
        if (lane == 0) { s_pf[wid] = cp; s_pf[NW + wid] = ls; s_pi[wid] = np; }
    }
    __syncthreads();
    if (tid == 0) {
        float cp = 0.0f, ls = 0.0f; int np = 0;
#pragma unroll
        for (int w = 0; w < NW; ++w) { cp += s_pf[w]; ls += s_pf[NW + w]; np += s_pi[w]; }
        s_scal[0] = cp; s_scal[1] = ls; s_npos = np;
    }
    __syncthreads();
    const int npos_row = s_npos;

    // ---- Phase E: exact top-k via 31-step bit-pattern bisection
    int k = 3 * npos_row;
    if (k > P_) k = P_;
    float hard_sum = 0.0f;
    if (k > 0) {
        long long lo = -1, hi = 0x7F800000LL;   // cnt(lo)>=k, cnt(hi)<k
        for (int it = 0; it < 31; ++it) {
            unsigned int mid = (unsigned int)((lo + hi) >> 1);
            int c = 0;
#pragma unroll
            for (int i = 0; i < NP9; ++i) c += (__float_as_uint(fv[i]) > mid) ? 1 : 0;
            c = wred_sum_i(c);
            if (lane == 0) s_cnt2[it & 1][wid] = c;
            __syncthreads();
            int cnt = 0;
#pragma unroll
            for (int w = 0; w < NW; ++w) cnt += s_cnt2[it & 1][w];
            if (cnt < k) hi = (lo + hi) >> 1; else lo = (lo + hi) >> 1;
        }
        unsigned int tbits = (unsigned int)hi;
        float tval = __uint_as_float(tbits);
        float lsum = 0.0f; int lcnt = 0;
#pragma unroll
        for (int i = 0; i < NP9; ++i) {
            if (__float_as_uint(fv[i]) > tbits) { lsum += fv[i]; lcnt++; }
        }
        lsum = wred_sum_f(lsum);
        lcnt = wred_sum_i(lcnt);
        if (lane == 0) { s_pf[wid] = lsum; s_pi[wid] = lcnt; }
        __syncthreads();
        if (tid == 0) {
            float sv = 0.0f; int sc2 = 0;
#pragma unroll
            for (int w = 0; w < NW; ++w) { sv += s_pf[w]; sc2 += s_pi[w]; }
            hard_sum = sv + (float)(k - sc2) * tval;
        }
    }

    // ---- finalize
    if (tid == 0) {
        float conf_row = s_scal[0] + hard_sum;
        float loc_row  = s_scal[1];
        out[3 + r] = (float)npos_row;
        atomicAdd(g_conf, conf_row);
        atomicAdd(g_loc,  loc_row);
        atomicAdd(g_np,   npos_row);
        __threadfence();
        unsigned int done = atomicAdd(g_cnt, 1u);
        if (done == B_ - 1) {
            float ct = atomicAdd(g_conf, 0.0f);
            float lt = atomicAdd(g_loc,  0.0f);
            int   np = atomicAdd(g_np,   0);
            float npt = (float)np;
            float conf_loss = ct / (1e-10f + npt);
            float loc_loss = (np > 0) ? lt / (4.0f * fmaxf(npt, 1.0f)) : 0.0f;
            out[0] = conf_loss + loc_loss;   // ALPHA = 1
            out[1] = conf_loss;
            out[2] = loc_loss;
        }
    }
}

extern "C" void kernel_launch(void* const* d_in, const int* in_sizes, int n_in,
                              void* d_out, int out_size, void* d_ws, size_t ws_size,
                              hipStream_t stream) {
    const float* plocs   = (const float*)d_in[0];  // (B,P,4)
    const float* pscores = (const float*)d_in[1];  // (B,P,3)
    const float* boxes   = (const float*)d_in[2];  // (B,M,4)
    const int*   labels  = (const int*)  d_in[3];  // (B,M)
    const float* priors  = (const float*)d_in[4];  // (P,4)
    float* out = (float*)d_out;

    // ws layout:
    //   [0,16)             g_cnt, g_conf, g_loc, g_np
    //   [1024, +64K)       cand[512*16] int2
    //   [66560, +128*P_)   objov bytes (~1.12 MB)
    char* ws = (char*)d_ws;
    unsigned int* g_cnt   = (unsigned int*)ws;
    float*        g_conf  = (float*)(ws + 4);
    float*        g_loc   = (float*)(ws + 8);
    int*          g_np    = (int*)(ws + 12);
    int2*         cand    = (int2*)(ws + 1024);
    unsigned char* objov  = (unsigned char*)(ws + 1024 + 512 * M_ * sizeof(int2));

    hipMemsetAsync(d_ws, 0, 16, stream);   // zero global accumulators
    mbox_match_kernel<<<4 * B_, NT, 0, stream>>>(boxes, priors, objov, cand);
    mbox_loss_kernel<<<B_, NT, 0, stream>>>(plocs, pscores, boxes, labels, priors,
                                            objov, cand, out,
                                            g_cnt, g_conf, g_loc, g_np);
}